// Round 5
// baseline (259.993 us; speedup 1.0000x reference)
//
#include <hip/hip_runtime.h>
#include <stdint.h>

#define BATCH 8192   // Gram K dimension
#define DIM   2048   // Gram M and N

typedef unsigned char  u8;
typedef unsigned int   u32;

using v8i  = __attribute__((ext_vector_type(8)))  int;
using v16f = __attribute__((ext_vector_type(16))) float;

// async global->LDS, 16B per lane; dest must be wave-uniform base + lane*16.
__device__ __forceinline__ void gl_lds16(const void* g, void* l) {
  __builtin_amdgcn_global_load_lds(
      (const __attribute__((address_space(1))) u32*)g,
      (__attribute__((address_space(3))) u32*)l, 16, 0, 0);
}

// ---------------------------------------------------------------------------
// Kernel 1: fused transpose + f32->fp8(e4m3) (round-4 proven, unchanged).
// src [8192 b][2048 d] f32 -> dst [2048 d][8192 b] fp8.
// ---------------------------------------------------------------------------
__global__ __launch_bounds__(256) void tcvt_kernel(
    const float* __restrict__ L, const float* __restrict__ T,
    u8* __restrict__ X, u8* __restrict__ Y)
{
  __shared__ u32 ls[64 * 68];

  const int tid = threadIdx.x;
  int id = blockIdx.x;
  const float* src;
  u8* dst;
  if (id < 1024) { src = L; dst = X; }
  else           { src = T; dst = Y; id -= 1024; }
  const int d0 = (id & 31) * 64;
  const int b0 = (id >> 5) * 256;

  const int s  = tid & 15;
  const int g  = tid >> 4;
  const int sw = s & 12;
#pragma unroll
  for (int j = 0; j < 4; ++j) {
    const int brow = j * 64 + g * 4;
    float4 f[4];
#pragma unroll
    for (int r = 0; r < 4; ++r)
      f[r] = *(const float4*)(src + (size_t)(b0 + brow + r) * DIM + d0 + s * 4);
    const int w = (j * 16 + g) ^ sw;
#pragma unroll
    for (int i = 0; i < 4; ++i) {
      const float* f0 = (const float*)&f[0];
      const float* f1 = (const float*)&f[1];
      const float* f2 = (const float*)&f[2];
      const float* f3 = (const float*)&f[3];
      u32 wv = __builtin_amdgcn_cvt_pk_fp8_f32(f0[i], f1[i], 0, false);
      wv     = __builtin_amdgcn_cvt_pk_fp8_f32(f2[i], f3[i], wv, true);
      ls[(s * 4 + i) * 68 + w] = wv;
    }
  }
  __syncthreads();

  const int d   = tid >> 2;
  const int g4  = tid & 3;
  const int sw2 = (d >> 2) & 12;
#pragma unroll
  for (int j2 = 0; j2 < 4; ++j2) {
    uint4 v = *(const uint4*)&ls[d * 68 + j2 * 16 + ((g4 * 4) ^ sw2)];
    *(uint4*)(dst + (size_t)(d0 + d) * BATCH + b0 + j2 * 64 + g4 * 16) = v;
  }
}

// ---------------------------------------------------------------------------
// Kernel 2: FUSED dual-Gram + dot. Each block: tile (i,j) of BOTH grams,
// FULL K=8192 (no k-split -> no cross terms, exact), dots c1.*c2 in-register.
// Grid 256 = 1 block/CU, 4 waves. Double-buffered LDS (2 x 4 panels x 16 KB
// = 128 KB): stage(it+1) issues right after the barrier, flies during
// compute(it) -> the compiler's vmcnt(0)-before-barrier drain is ~free.
// Indexing identical to round-4's proven swizzle (chunk p of row r holds
// global chunk p ^ (r&7); fragment chunks lc ^ (ra&7)).
// Layout-agnostic: c1,c2 share the same lane-slot->(i,j) map, so sum of
// products is exact regardless of the MFMA C/D layout.
// ---------------------------------------------------------------------------
__global__ __launch_bounds__(256, 1) void gram_fused(
    const u8* __restrict__ X, const u8* __restrict__ Y,
    float* __restrict__ d_acc, u32* __restrict__ d_cnt,
    float* __restrict__ out)
{
  __shared__ u8 ls[2][4][16384];   // [buf][panel: Xi,Xj,Yi,Yj][128 rows x 128 k]
  __shared__ float red[4];

  const int tid = threadIdx.x;
  const int t   = blockIdx.x;       // 0..255
  const int i0  = (t >> 4) * 128;
  const int j0  = (t & 15) * 128;

  const int wave = tid >> 6;
  const int lane = tid & 63;
  const int wr = (wave >> 1) * 64;
  const int wc = (wave & 1) * 64;
  const int lr = lane & 31;
  const int kh = lane >> 5;

  // Staging offsets: each panel 16 KB = 4 rounds x 256 lanes x 16 B.
  u32 sdst[4], soi[4], soj[4];
#pragma unroll
  for (int rr = 0; rr < 4; ++rr) {
    const int li  = rr * 256 + tid;
    const int row = li >> 3;
    const int p   = li & 7;
    const int gc  = p ^ (row & 7);
    sdst[rr] = (u32)(row * 128 + p * 16);
    soi[rr]  = (u32)(i0 + row) * BATCH + gc * 16;
    soj[rr]  = (u32)(j0 + row) * BATCH + gc * 16;
  }

  // Fragment LDS byte offsets within a panel: [half][kstep][chunk].
  u32 fa[2][2][2], fb[2][2][2];
#pragma unroll
  for (int h = 0; h < 2; ++h) {
    const int ra = wr + h * 32 + lr;
    const int rb = wc + h * 32 + lr;
#pragma unroll
    for (int ks = 0; ks < 2; ++ks)
#pragma unroll
      for (int c = 0; c < 2; ++c) {
        const int lc = ks * 4 + kh * 2 + c;
        fa[h][ks][c] = (u32)(ra * 128 + (lc ^ (ra & 7)) * 16);
        fb[h][ks][c] = (u32)(rb * 128 + (lc ^ (rb & 7)) * 16);
      }
  }

  v16f c1[2][2] = {};
  v16f c2[2][2] = {};
  const int sc = 0x7F7F7F7F;        // e8m0 = 127 -> scale 1.0

  // Prologue: stage k-iter 0 into buffer 0.
#pragma unroll
  for (int rr = 0; rr < 4; ++rr) {
    gl_lds16(X + soi[rr], &ls[0][0][sdst[rr]]);
    gl_lds16(X + soj[rr], &ls[0][1][sdst[rr]]);
    gl_lds16(Y + soi[rr], &ls[0][2][sdst[rr]]);
    gl_lds16(Y + soj[rr], &ls[0][3][sdst[rr]]);
  }

  for (int it = 0; it < 64; ++it) {
    __syncthreads();                 // drains staging of buf, frees buf^1
    const int buf = it & 1;
    if (it < 63) {
      const u32 k1 = (u32)(it + 1) * 128;
#pragma unroll
      for (int rr = 0; rr < 4; ++rr) {
        gl_lds16(X + soi[rr] + k1, &ls[buf ^ 1][0][sdst[rr]]);
        gl_lds16(X + soj[rr] + k1, &ls[buf ^ 1][1][sdst[rr]]);
        gl_lds16(Y + soi[rr] + k1, &ls[buf ^ 1][2][sdst[rr]]);
        gl_lds16(Y + soj[rr] + k1, &ls[buf ^ 1][3][sdst[rr]]);
      }
    }

    const u8* pXi = ls[buf][0];
    const u8* pXj = ls[buf][1];
    const u8* pYi = ls[buf][2];
    const u8* pYj = ls[buf][3];
#pragma unroll
    for (int ks = 0; ks < 2; ++ks) {
      v8i ax[2], bx[2], ay[2], by[2];
#pragma unroll
      for (int h = 0; h < 2; ++h) {
        int4 lo, hi;
        lo = *(const int4*)&pXi[fa[h][ks][0]];
        hi = *(const int4*)&pXi[fa[h][ks][1]];
        ax[h] = (v8i){lo.x, lo.y, lo.z, lo.w, hi.x, hi.y, hi.z, hi.w};
        lo = *(const int4*)&pXj[fb[h][ks][0]];
        hi = *(const int4*)&pXj[fb[h][ks][1]];
        bx[h] = (v8i){lo.x, lo.y, lo.z, lo.w, hi.x, hi.y, hi.z, hi.w};
        lo = *(const int4*)&pYi[fa[h][ks][0]];
        hi = *(const int4*)&pYi[fa[h][ks][1]];
        ay[h] = (v8i){lo.x, lo.y, lo.z, lo.w, hi.x, hi.y, hi.z, hi.w};
        lo = *(const int4*)&pYj[fb[h][ks][0]];
        hi = *(const int4*)&pYj[fb[h][ks][1]];
        by[h] = (v8i){lo.x, lo.y, lo.z, lo.w, hi.x, hi.y, hi.z, hi.w};
      }
#pragma unroll
      for (int h = 0; h < 2; ++h)
#pragma unroll
        for (int hc = 0; hc < 2; ++hc) {
          c1[h][hc] = __builtin_amdgcn_mfma_scale_f32_32x32x64_f8f6f4(
              ax[h], bx[hc], c1[h][hc], 0, 0, 0, sc, 0, sc);
          c2[h][hc] = __builtin_amdgcn_mfma_scale_f32_32x32x64_f8f6f4(
              ay[h], by[hc], c2[h][hc], 0, 0, 0, sc, 0, sc);
        }
    }
  }

  // In-register dot of the two gram tiles, then block/device reduction.
  float s = 0.0f;
#pragma unroll
  for (int h = 0; h < 2; ++h)
#pragma unroll
    for (int hc = 0; hc < 2; ++hc)
#pragma unroll
      for (int i = 0; i < 16; ++i)
        s += c1[h][hc][i] * c2[h][hc][i];

#pragma unroll
  for (int off = 32; off > 0; off >>= 1)
    s += __shfl_down(s, off);
  if (lane == 0) red[wave] = s;
  __syncthreads();

  if (tid == 0) {
    atomicAdd(d_acc, red[0] + red[1] + red[2] + red[3]);
    __threadfence();
    const u32 old = atomicAdd(d_cnt, 1u);
    if (old == 255u) {                       // last of 256 blocks
      float S   = atomicAdd(d_acc, 0.0f);    // device-coherent read
      float fid = S * (1.0f / ((float)BATCH * (float)BATCH));
      fid = fminf(fmaxf(fid, 0.0f), 1.0f);
      *out = 0.1f * fabsf(fid - 0.95f);
    }
  }
}

extern "C" void kernel_launch(void* const* d_in, const int* in_sizes, int n_in,
                              void* d_out, int out_size, void* d_ws, size_t ws_size,
                              hipStream_t stream) {
  const float* L = (const float*)d_in[0];
  const float* T = (const float*)d_in[1];
  float* out = (float*)d_out;

  const size_t NEL = (size_t)BATCH * DIM;    // 16,777,216 per tensor (fp8 bytes)
  u8*    X   = (u8*)d_ws;                    // L^T fp8 [2048][8192]
  u8*    Y   = (u8*)d_ws + NEL;              // T^T fp8 [2048][8192]
  float* acc = (float*)((char*)d_ws + 2 * NEL);
  u32*   cnt = (u32*)((char*)d_ws + 2 * NEL + sizeof(float));

  hipMemsetAsync(acc, 0, 2 * sizeof(u32), stream);   // zero acc + ticket
  tcvt_kernel<<<2048, 256, 0, stream>>>(L, T, X, Y);
  gram_fused<<<256, 256, 0, stream>>>(X, Y, acc, cnt, out);
}

// Round 6
// 231.323 us; speedup vs baseline: 1.1239x; 1.1239x over previous
//
#include <hip/hip_runtime.h>
#include <stdint.h>

#define BATCH 8192   // Gram K dimension
#define DIM   2048   // Gram M and N

typedef unsigned char  u8;
typedef unsigned short u16;
typedef unsigned int   u32;

using v8i  = __attribute__((ext_vector_type(8)))  int;
using v16f = __attribute__((ext_vector_type(16))) float;

// async global->LDS, 16B per lane; dest must be wave-uniform base + lane*16.
__device__ __forceinline__ void gl_lds16(const void* g, void* l) {
  __builtin_amdgcn_global_load_lds(
      (const __attribute__((address_space(1))) u32*)g,
      (__attribute__((address_space(3))) u32*)l, 16, 0, 0);
}

// f32 -> fp4 e2m1 nibble of (64*x), round-to-nearest (midpoint thresholds).
// e2m1 index==encoding: {0,0.5,1,1.5,2,3,4,6}, clip at 6.
__device__ __forceinline__ u32 nib4(float x) {
  float xs = x * 64.0f;
  float a  = fabsf(xs);
  u32 n = (u32)(a >= 0.25f) + (u32)(a >= 0.75f) + (u32)(a >= 1.25f) +
          (u32)(a >= 1.75f) + (u32)(a >= 2.5f)  + (u32)(a >= 3.5f)  +
          (u32)(a >= 5.0f);
  return n | (xs < 0.0f ? 8u : 0u);
}

// ---------------------------------------------------------------------------
// Kernel 1: fused transpose + f32->fp4(e2m1, pre-scaled by 64).
// src [8192 b][2048 d] f32 -> dst [2048 d][8192 b-fp4] (4096 B/row).
// Block tile 64d x 256b (round-4 proven structure, nibble-packed).
// Phase A: read f32 coalesced along d, 4x4 micro-transpose, pack 4 nibbles
// per u16, write LDS column w = (j*16+g) ^ (s&12) (2-way-free swizzle).
// Phase B: read two uint2 (unswizzled groups), store uint4 coalesced along b.
// ---------------------------------------------------------------------------
__global__ __launch_bounds__(256) void tcvt_fp4(
    const float* __restrict__ L, const float* __restrict__ T,
    u8* __restrict__ X, u8* __restrict__ Y)
{
  __shared__ u16 ls[64 * 68];   // [d][64 u16 payload + 4 pad]

  const int tid = threadIdx.x;
  int id = blockIdx.x;
  const float* src;
  u8* dst;
  if (id < 1024) { src = L; dst = X; }
  else           { src = T; dst = Y; id -= 1024; }
  const int d0 = (id & 31) * 64;
  const int b0 = (id >> 5) * 256;

  const int s  = tid & 15;          // d-slot (d = 4s..4s+3)
  const int g  = tid >> 4;          // b row-group
  const int sw = s & 12;
#pragma unroll
  for (int j = 0; j < 4; ++j) {
    const int brow = j * 64 + g * 4;
    float4 f[4];
#pragma unroll
    for (int r = 0; r < 4; ++r)
      f[r] = *(const float4*)(src + (size_t)(b0 + brow + r) * DIM + d0 + s * 4);
    const int w = (j * 16 + g) ^ sw;   // u16 column 0..63
    const float* fp[4] = {(const float*)&f[0], (const float*)&f[1],
                          (const float*)&f[2], (const float*)&f[3]};
#pragma unroll
    for (int i = 0; i < 4; ++i) {
      u32 v = nib4(fp[0][i]) | (nib4(fp[1][i]) << 4) |
              (nib4(fp[2][i]) << 8) | (nib4(fp[3][i]) << 12);
      ls[(s * 4 + i) * 68 + w] = (u16)v;
    }
  }
  __syncthreads();

  // Phase B: row d has 64 u16 = 128 B of fp4; swizzle was on u16-column
  // bits 2..3 with mask (row>>2)&12 -> group-of-4 swizzle gsw = (row>>4)&3.
#pragma unroll
  for (int j2 = 0; j2 < 2; ++j2) {
    const int d   = (tid >> 3) + j2 * 32;
    const int o8  = tid & 7;
    const int gsw = (d >> 4) & 3;
    const int g1  = (2 * o8)     ^ gsw;
    const int g2  = (2 * o8 + 1) ^ gsw;
    uint2 a = *(const uint2*)&ls[d * 68 + g1 * 4];
    uint2 b = *(const uint2*)&ls[d * 68 + g2 * 4];
    uint4 v = {a.x, a.y, b.x, b.y};
    *(uint4*)(dst + (size_t)(d0 + d) * (BATCH / 2) + (b0 >> 1) + o8 * 16) = v;
  }
}

// ---------------------------------------------------------------------------
// Kernel 2: Gram tile, materialized (round-4 structure), MX-fp4 operands,
// double-buffered LDS (2 x 2 panels x 8 KB = 32 KB/block, 2 blocks/CU,
// ONE barrier per k-iter). G = M M^T, M = [2048][8192-fp4], K=8192, BK=128
// (= 64 B/row/iter). Wave = 64x64 quadrant = 2x2 x 2ks of
// mfma_scale_f32_32x32x64_f8f6f4 with cbsz=blgp=4 (fp4), payload in v[0:3].
// LDS row = 64 B = 4 chunks; chunk p of row r holds global chunk p ^ (r&3)
// -> fragment b128 reads hit every bank exactly once per 4-row group (floor).
// Tile stored in lane-slot order (layout-agnostic; both grams identical).
// ---------------------------------------------------------------------------
__global__ __launch_bounds__(256, 2) void gram_fp4(
    const u8* __restrict__ X, const u8* __restrict__ Y,
    float* __restrict__ Gx, float* __restrict__ Gy)
{
  __shared__ u8 ls[2][2][8192];   // [buf][panel I/J][128 rows x 64 B]

  const int tid = threadIdx.x;
  const int bid = blockIdx.x;
  const int t   = bid & 255;
  const u8*  src = (bid < 256) ? X : Y;
  float*     dst = (bid < 256) ? Gx : Gy;
  const int i0  = (t >> 4) * 128;
  const int j0  = (t & 15) * 128;

  const int wave = tid >> 6;
  const int lane = tid & 63;
  const int wr = (wave >> 1) * 64;
  const int wc = (wave & 1) * 64;
  const int lr = lane & 31;
  const int kh = lane >> 5;          // 16B k-chunk half within ks-step

  // Staging: 8 KB/panel = 2 rounds x 256 lanes x 16 B.
  u32 sdst[2], soi[2], soj[2];
#pragma unroll
  for (int rr = 0; rr < 2; ++rr) {
    const int li  = rr * 256 + tid;
    const int row = li >> 2;          // 4 chunks of 16B per 64B row
    const int p   = li & 3;
    const int gc  = p ^ (row & 3);
    sdst[rr] = (u32)(row * 64 + p * 16);
    soi[rr]  = (u32)(i0 + row) * (BATCH / 2) + gc * 16;
    soj[rr]  = (u32)(j0 + row) * (BATCH / 2) + gc * 16;
  }

  // Fragment LDS byte addresses: [half][ks], one b128 each (16B payload).
  u32 fa[2][2], fb[2][2];
#pragma unroll
  for (int h = 0; h < 2; ++h) {
    const int ra = wr + h * 32 + lr;
    const int rb = wc + h * 32 + lr;
#pragma unroll
    for (int ks = 0; ks < 2; ++ks) {
      const int c = 2 * ks + kh;      // logical 16B chunk 0..3
      fa[h][ks] = (u32)(ra * 64 + (c ^ (ra & 3)) * 16);
      fb[h][ks] = (u32)(rb * 64 + (c ^ (rb & 3)) * 16);
    }
  }

  v16f acc[2][2] = {};
  const int sc = 0x7F7F7F7F;          // e8m0 = 127 -> scale 1.0

  // Prologue: stage k-iter 0 into buffer 0.
#pragma unroll
  for (int rr = 0; rr < 2; ++rr) {
    gl_lds16(src + soi[rr], &ls[0][0][sdst[rr]]);
    gl_lds16(src + soj[rr], &ls[0][1][sdst[rr]]);
  }

  for (int it = 0; it < 64; ++it) {
    __syncthreads();                  // staging of buf complete; buf^1 free
    const int buf = it & 1;
    if (it < 63) {
      const u32 k1 = (u32)(it + 1) * 64;   // 64 B of fp4 = 128 k per iter
#pragma unroll
      for (int rr = 0; rr < 2; ++rr) {
        gl_lds16(src + soi[rr] + k1, &ls[buf ^ 1][0][sdst[rr]]);
        gl_lds16(src + soj[rr] + k1, &ls[buf ^ 1][1][sdst[rr]]);
      }
    }
    const u8* pI = ls[buf][0];
    const u8* pJ = ls[buf][1];
#pragma unroll
    for (int ks = 0; ks < 2; ++ks) {
      v8i a[2], b[2];
#pragma unroll
      for (int h = 0; h < 2; ++h) {
        int4 pa = *(const int4*)&pI[fa[h][ks]];
        a[h] = (v8i){pa.x, pa.y, pa.z, pa.w, 0, 0, 0, 0};
        int4 pb = *(const int4*)&pJ[fb[h][ks]];
        b[h] = (v8i){pb.x, pb.y, pb.z, pb.w, 0, 0, 0, 0};
      }
#pragma unroll
      for (int h = 0; h < 2; ++h)
#pragma unroll
        for (int hc = 0; hc < 2; ++hc)
          acc[h][hc] = __builtin_amdgcn_mfma_scale_f32_32x32x64_f8f6f4(
              a[h], b[hc], acc[h][hc], /*cbsz=fp4*/ 4, /*blgp=fp4*/ 4,
              0, sc, 0, sc);
    }
  }

  // Store tile in lane-slot order (both grams identical -> dot invariant).
  float4* o = (float4*)(dst + (size_t)t * 16384);
#pragma unroll
  for (int h = 0; h < 2; ++h)
#pragma unroll
    for (int hc = 0; hc < 2; ++hc)
#pragma unroll
      for (int r4 = 0; r4 < 4; ++r4) {
        float4 v = {acc[h][hc][r4 * 4 + 0], acc[h][hc][r4 * 4 + 1],
                    acc[h][hc][r4 * 4 + 2], acc[h][hc][r4 * 4 + 3]};
        o[((h * 2 + hc) * 4 + r4) * 256 + tid] = v;
      }
}

// ---------------------------------------------------------------------------
// Kernel 3: elementwise dot of the two materialized Grams -> scalar.
// ---------------------------------------------------------------------------
__global__ __launch_bounds__(256) void dot_kernel(
    const float4* __restrict__ Gx, const float4* __restrict__ Gy,
    float* __restrict__ d_acc)
{
  __shared__ float red[4];
  const int tid  = threadIdx.x;
  const int lane = tid & 63;
  const int i0   = blockIdx.x * 256 + tid;
  float s = 0.0f;
#pragma unroll
  for (int j = 0; j < 4; ++j) {
    float4 a = Gx[i0 + j * 262144];
    float4 b = Gy[i0 + j * 262144];
    s += a.x * b.x + a.y * b.y + a.z * b.z + a.w * b.w;
  }
#pragma unroll
  for (int off = 32; off > 0; off >>= 1)
    s += __shfl_down(s, off);
  if (lane == 0) red[tid >> 6] = s;
  __syncthreads();
  if (tid == 0)
    atomicAdd(d_acc, red[0] + red[1] + red[2] + red[3]);
}

__global__ void finalize_kernel(const float* __restrict__ acc, float* __restrict__ out) {
  // fidelity = S / (B^2 * 64^4) = S * 2^-50  (B^2 = 2^26, c^4 = 2^24)
  float fid = acc[0] * 0x1.0p-50f;
  fid = fminf(fmaxf(fid, 0.0f), 1.0f);
  out[0] = 0.1f * fabsf(fid - 0.95f);
}

extern "C" void kernel_launch(void* const* d_in, const int* in_sizes, int n_in,
                              void* d_out, int out_size, void* d_ws, size_t ws_size,
                              hipStream_t stream) {
  const float* L = (const float*)d_in[0];
  const float* T = (const float*)d_in[1];
  float* out = (float*)d_out;

  const size_t NF4 = (size_t)BATCH * DIM / 2;    // 8,388,608 B per fp4 tensor
  const size_t GEL = (size_t)DIM * DIM;          // 4,194,304 floats per Gram
  // ws: X,Y fp4 (16 MB) + Gx,Gy f32 (33.5 MB) + acc -> ~48 MB (ws >= 64 MB).
  u8*    X   = (u8*)d_ws;
  u8*    Y   = (u8*)d_ws + NF4;
  float* Gx  = (float*)((char*)d_ws + 2 * NF4);
  float* Gy  = Gx + GEL;
  float* acc = Gy + GEL;

  hipMemsetAsync(acc, 0, sizeof(float), stream);
  tcvt_fp4<<<2048, 256, 0, stream>>>(L, T, X, Y);
  gram_fp4<<<512, 256, 0, stream>>>(X, Y, Gx, Gy);
  dot_kernel<<<1024, 256, 0, stream>>>((const float4*)Gx, (const float4*)Gy, acc);
  finalize_kernel<<<1, 1, 0, stream>>>(acc, out);
}